// Round 15
// baseline (268.114 us; speedup 1.0000x reference)
//
#include <hip/hip_runtime.h>
#include <math.h>

#define NN 10000
#define GG 12
#define CC 64
#define AA 3
#define EE 50000
#define LN_EPS 1e-5f
#define MAXDEG 64   // max in-degree cap; Poisson(E/N=5) max ~17, 64 is far beyond

typedef __attribute__((ext_vector_type(4))) float f4;
typedef __attribute__((ext_vector_type(4))) short s4;

union S4U { s4 s; unsigned int w[2]; };
union I2S { int i[2]; s4 s; };

// pack 4 f32 -> 4 bf16 (truncation) in frag element order k0..k3
__device__ __forceinline__ s4 pack4(float k0, float k1, float k2, float k3) {
    S4U t;
    t.w[0] = __builtin_amdgcn_perm(__float_as_uint(k1), __float_as_uint(k0), 0x07060302u);
    t.w[1] = __builtin_amdgcn_perm(__float_as_uint(k3), __float_as_uint(k2), 0x07060302u);
    return t.s;
}
// pack 2 f32 -> one dword [bf16(a) | bf16(b)<<16]
__device__ __forceinline__ unsigned int pack2(float a, float b) {
    return __builtin_amdgcn_perm(__float_as_uint(b), __float_as_uint(a), 0x07060302u);
}

__device__ __forceinline__ f4 mfma_bf16(s4 a, s4 b, f4 c) {
#if __has_builtin(__builtin_amdgcn_mfma_f32_16x16x16bf16_1k)
    return __builtin_amdgcn_mfma_f32_16x16x16bf16_1k(a, b, c, 0, 0, 0);
#else
    asm volatile("v_mfma_f32_16x16x16_bf16 %0, %1, %2, %0" : "+v"(c) : "v"(a), "v"(b));
    return c;
#endif
}

// ---------------- kernel 1: xpack (+ zero cnt, fused) ----------------
__global__ __launch_bounds__(256) void xpack(const float* __restrict__ x,
                                             unsigned int* __restrict__ xp,
                                             int* __restrict__ cnt) {
    const int gid = blockIdx.x * 256 + threadIdx.x;
    if (gid < NN) cnt[gid] = 0;

    const int l  = threadIdx.x & 63;
    const int n  = blockIdx.x * 4 + (threadIdx.x >> 6);
    const int lm = l & 15;
    const int lg = l >> 4;

    unsigned int d[8];
    if (lg < 3) {
        const char* xb = (const char*)(x + n * (GG * CC)) + lg * 1024 + lm * 4;
#pragma unroll
        for (int t = 0; t < 4; ++t) {
            const float v0 = *(const float*)(xb + t * 64 + 0 * 256);
            const float v1 = *(const float*)(xb + t * 64 + 1 * 256);
            const float v2 = *(const float*)(xb + t * 64 + 2 * 256);
            const float v3 = *(const float*)(xb + t * 64 + 3 * 256);
            d[2 * t]     = pack2(v0, v1);
            d[2 * t + 1] = pack2(v2, v3);
        }
    } else {
#pragma unroll
        for (int k = 0; k < 8; ++k) d[k] = 0u;
    }
    unsigned int* o = xp + (size_t)n * 512 + l * 8;
    *(uint4*)o       = make_uint4(d[0], d[1], d[2], d[3]);
    *(uint4*)(o + 4) = make_uint4(d[4], d[5], d[6], d[7]);
}

// ---------------- kernel 2: bucket edges by destination; pack e | src<<17 ----------------
__global__ __launch_bounds__(256) void bucket_fill(const int* __restrict__ ei,
                                                   int* __restrict__ cnt,
                                                   int* __restrict__ elist) {
    int e = blockIdx.x * 256 + threadIdx.x;
    if (e < EE) {
        int src = ei[e];
        int dst = ei[EE + e];
        int pos = atomicAdd(&cnt[dst], 1);
        if (pos < MAXDEG) elist[dst * MAXDEG + pos] = e | (src << 17);
    }
}

// ---------------- kernel 3: conv via MFMA — block edge-queue + LDS-atomic reduce ----
// block = 4 nodes, 4 waves. Queue = concat of the 4 nodes' packed edge lists
// (prefix-sum in LDS); all waves stride the queue (i = w, w+4, ...) -> load
// balance decoupled from per-node degree. Per edge: one 12-MFMA pass (C=0),
// Wk combine, 16 predicated ds_add_f32 into the node's padded LDS accumulator
// (stride 68 -> 2-way bank pattern = free). Depth-2 pipeline on the verified
// r12 datapath. Epilogue: coalesced LDS->global copy (agg layout is linear).
__global__ __launch_bounds__(256) void conv_mfma(
    const unsigned int* __restrict__ xp, const float* __restrict__ attr,
    const float* __restrict__ Wk,
    const int* __restrict__ cnt, const int* __restrict__ elist,
    float* __restrict__ agg) {
    __shared__ float lsa[4][2][432];            // 13.8 KB: per-wave attr slots
    __shared__ float nacc[4][GG][68];           // 13.1 KB: padded node accumulators
    __shared__ int   qp_[4 * MAXDEG];           // 1 KB: packed edge queue
    __shared__ int   qn_[4 * MAXDEG];           // 1 KB: node-slot per entry
    __shared__ int   degs[4];

    const int l  = threadIdx.x & 63;
    const int w  = threadIdx.x >> 6;
    const int n  = blockIdx.x * 4 + w;
    const int lm = l & 15;
    const int lg = l >> 4;

    const int fbase = (lm < 12 && lg < 3) ? (lm * 36 + lg * 12) : 0;
    const int a1l   = (l < 44) ? l : 43;

    const int deg = min(cnt[n], MAXDEG);
    const int myE = elist[n * MAXDEG + l];      // lane l holds entry l
    if (l == 0) degs[w] = deg;

    // zero accumulators (4*12*68 = 3264 floats = 816 f4)
    {
        float* nf = &nacc[0][0][0];
        const f4 z4 = (f4){0.f, 0.f, 0.f, 0.f};
        for (int q = threadIdx.x; q < 816; q += 256) *(f4*)(nf + q * 4) = z4;
    }
    __syncthreads();

    int off = 0, total = 0;
#pragma unroll
    for (int j = 0; j < 4; ++j) {
        const int d = degs[j];
        if (j < w) off += d;
        total += d;
    }
    if (l < deg) { qp_[off + l] = myE; qn_[off + l] = w; }
    __syncthreads();

    // loop-invariant Wk fragments
    float wk[3][4];
#pragma unroll
    for (int a = 0; a < 3; ++a)
#pragma unroll
        for (int t = 0; t < 4; ++t)
            wk[a][t] = Wk[a * CC + lm + 16 * t];

    const int cntLoc = (total > w) ? ((total - w + 3) >> 2) : 0;

    int Pa = 0, Sa = 0, Pb = 0, Sb = 0;
    f4 Aa0, Aa1, Ab0, Ab1;
    int4 Xa0, Xa1, Xb0, Xb1;

#define QLOAD(k, P, S, A0, A1, X0, X1)                                          \
    {                                                                           \
        const int qi = w + 4 * (k);                                             \
        P = __builtin_amdgcn_readfirstlane(qp_[qi]);                            \
        S = __builtin_amdgcn_readfirstlane(qn_[qi]);                            \
        const char* ab = (const char*)(attr + (size_t)(P & 0x1FFFF) * 432);     \
        A0 = *(const f4*)(ab + 16 * l);                                         \
        A1 = *(const f4*)(ab + 1024 + 16 * a1l);                                \
        const int* xb = (const int*)(xp + (size_t)(P >> 17) * 512 + 8 * l);     \
        X0 = *(const int4*)xb;                                                  \
        X1 = *(const int4*)(xb + 4);                                            \
    }

#define STAGE(slot, A0, A1)                                                     \
    {                                                                           \
        float* sw = &lsa[w][slot][0];                                           \
        *(f4*)(sw + 4 * l) = A0;                                                \
        if (l < 44) *(f4*)(sw + 256 + 4 * l) = A1;                              \
    }

#define COMPUTE(slot, S, X0, X1)                                                \
    {                                                                           \
        I2S u0, u1, u2, u3;                                                     \
        u0.i[0] = X0.x; u0.i[1] = X0.y;                                         \
        u1.i[0] = X0.z; u1.i[1] = X0.w;                                         \
        u2.i[0] = X1.x; u2.i[1] = X1.y;                                         \
        u3.i[0] = X1.z; u3.i[1] = X1.w;                                         \
        const float* sr = &lsa[w][slot][0] + fbase;                             \
        const f4 q0 = *(const f4*)(sr);                                         \
        const f4 q1 = *(const f4*)(sr + 4);                                     \
        const f4 q2 = *(const f4*)(sr + 8);                                     \
        const s4 af0 = pack4(q0[0], q0[3], q1[2], q2[1]);                       \
        const s4 af1 = pack4(q0[1], q1[0], q1[3], q2[2]);                       \
        const s4 af2 = pack4(q0[2], q1[1], q2[0], q2[3]);                       \
        const f4 z4 = (f4){0.f, 0.f, 0.f, 0.f};                                 \
        f4 acc[3][4];                                                           \
        acc[0][0] = mfma_bf16(af0, u0.s, z4);                                   \
        acc[1][0] = mfma_bf16(af1, u0.s, z4);                                   \
        acc[2][0] = mfma_bf16(af2, u0.s, z4);                                   \
        acc[0][1] = mfma_bf16(af0, u1.s, z4);                                   \
        acc[1][1] = mfma_bf16(af1, u1.s, z4);                                   \
        acc[2][1] = mfma_bf16(af2, u1.s, z4);                                   \
        acc[0][2] = mfma_bf16(af0, u2.s, z4);                                   \
        acc[1][2] = mfma_bf16(af1, u2.s, z4);                                   \
        acc[2][2] = mfma_bf16(af2, u2.s, z4);                                   \
        acc[0][3] = mfma_bf16(af0, u3.s, z4);                                   \
        acc[1][3] = mfma_bf16(af1, u3.s, z4);                                   \
        acc[2][3] = mfma_bf16(af2, u3.s, z4);                                   \
        _Pragma("unroll")                                                       \
        for (int t = 0; t < 4; ++t) {                                           \
            _Pragma("unroll")                                                   \
            for (int r = 0; r < 4; ++r) {                                       \
                const float mv = fmaf(acc[0][t][r], wk[0][t],                   \
                                 fmaf(acc[1][t][r], wk[1][t],                   \
                                      acc[2][t][r] * wk[2][t]));                \
                if (lg < 3)                                                     \
                    atomicAdd(&nacc[S][lg * 4 + r][lm + 16 * t], mv);           \
            }                                                                   \
        }                                                                       \
    }

    if (cntLoc > 0) QLOAD(0, Pa, Sa, Aa0, Aa1, Xa0, Xa1);
    if (cntLoc > 1) QLOAD(1, Pb, Sb, Ab0, Ab1, Xb0, Xb1);
    if (cntLoc > 0) STAGE(0, Aa0, Aa1);

    for (int k = 0; k < cntLoc; k += 2) {
        COMPUTE(0, Sa, Xa0, Xa1);
        if (k + 2 < cntLoc) QLOAD(k + 2, Pa, Sa, Aa0, Aa1, Xa0, Xa1);
        if (k + 1 < cntLoc) {
            STAGE(1, Ab0, Ab1);
            COMPUTE(1, Sb, Xb0, Xb1);
            if (k + 3 < cntLoc) QLOAD(k + 3, Pb, Sb, Ab0, Ab1, Xb0, Xb1);
            if (k + 2 < cntLoc) STAGE(0, Aa0, Aa1);
        }
    }

#undef QLOAD
#undef STAGE
#undef COMPUTE

    __syncthreads();

    // ---- coalesced LDS -> global copy (agg layout [n][g][c] is linear) ----
    float* ob = agg + (size_t)blockIdx.x * 4 * (GG * CC);
#pragma unroll
    for (int q = 0; q < 3; ++q) {
        const int fi  = threadIdx.x + q * 256;     // 0..767 f4 (= 4*768 floats)
        const int s   = fi / 192;
        const int rem = fi % 192;
        const int g   = rem / 16;
        const int c4  = (rem % 16) * 4;
        *(f4*)(ob + fi * 4) = *(const f4*)(&nacc[s][g][c4]);
    }
}

// ---------------- kernel 4: LN + MLP via MFMA — 512-thr blocks (verified) ----------------
__global__ __launch_bounds__(512) void ln_mlp_mfma(
    const float* __restrict__ x, const float* __restrict__ cb,
    const float* __restrict__ lnw, const float* __restrict__ lnb,
    const float* __restrict__ W1, const float* __restrict__ b1,
    const float* __restrict__ W2, const float* __restrict__ b2,
    const float* __restrict__ ls, float* __restrict__ out) {
    __shared__ float sbuf[8][16 * 68];          // 34.8 KB

    const int l  = threadIdx.x & 63;
    const int wv = threadIdx.x >> 6;
    const int lm = l & 15;
    const int lg = l >> 4;
    const int f0 = (blockIdx.x * 8 + wv) * 16;
    if (f0 >= NN * GG) return;                  // tail guard (whole wave)

    const float* aggp = out + (size_t)(f0 + lm) * CC + 4 * lg;
    f4 h4[4];
#pragma unroll
    for (int kt = 0; kt < 4; ++kt) h4[kt] = *(const f4*)(aggp + 16 * kt);

    f4 cb4[4], lw4[4], lb4[4];
#pragma unroll
    for (int kt = 0; kt < 4; ++kt) {
        cb4[kt] = *(const f4*)(cb  + 4 * lg + 16 * kt);
        lw4[kt] = *(const f4*)(lnw + 4 * lg + 16 * kt);
        lb4[kt] = *(const f4*)(lnb + 4 * lg + 16 * kt);
    }

    float s = 0.f, s2 = 0.f;
#pragma unroll
    for (int kt = 0; kt < 4; ++kt)
#pragma unroll
        for (int j = 0; j < 4; ++j) {
            const float v = h4[kt][j] + cb4[kt][j];
            h4[kt][j] = v;
            s += v; s2 += v * v;
        }
    s  += __shfl_xor(s, 16);  s  += __shfl_xor(s, 32);
    s2 += __shfl_xor(s2, 16); s2 += __shfl_xor(s2, 32);
    const float mu  = s * (1.f / 64.f);
    const float inv = rsqrtf(s2 * (1.f / 64.f) - mu * mu + LN_EPS);

    s4 hf[4];
#pragma unroll
    for (int kt = 0; kt < 4; ++kt) {
        const float n0 = (h4[kt][0] - mu) * inv * lw4[kt][0] + lb4[kt][0];
        const float n1 = (h4[kt][1] - mu) * inv * lw4[kt][1] + lb4[kt][1];
        const float n2 = (h4[kt][2] - mu) * inv * lw4[kt][2] + lb4[kt][2];
        const float n3 = (h4[kt][3] - mu) * inv * lw4[kt][3] + lb4[kt][3];
        hf[kt] = pack4(n0, n1, n2, n3);
    }

    s4 w1f[4][4];
#pragma unroll
    for (int mt = 0; mt < 4; ++mt)
#pragma unroll
        for (int kt = 0; kt < 4; ++kt) {
            const int kb = 4 * lg + 16 * kt;
            const int m  = lm + 16 * mt;
            w1f[mt][kt] = pack4(W1[(kb + 0) * CC + m], W1[(kb + 1) * CC + m],
                                W1[(kb + 2) * CC + m], W1[(kb + 3) * CC + m]);
        }

    f4 z[4];
#pragma unroll
    for (int mt = 0; mt < 4; ++mt) z[mt] = (f4){0.f, 0.f, 0.f, 0.f};
#pragma unroll
    for (int mt = 0; mt < 4; ++mt)
#pragma unroll
        for (int kt = 0; kt < 4; ++kt)
            z[mt] = mfma_bf16(w1f[mt][kt], hf[kt], z[mt]);

    s4 gf[4];
#pragma unroll
    for (int mt = 0; mt < 4; ++mt) {
        const f4 b14 = *(const f4*)(b1 + 16 * mt + 4 * lg);
        float g[4];
#pragma unroll
        for (int r = 0; r < 4; ++r) {
            const float zz = z[mt][r] + b14[r];
            g[r] = 0.5f * zz * (1.f + erff(zz * 0.70710678118654752f));
        }
        gf[mt] = pack4(g[0], g[1], g[2], g[3]);
    }

    s4 w2f[4][4];
#pragma unroll
    for (int mt = 0; mt < 4; ++mt)
#pragma unroll
        for (int kt = 0; kt < 4; ++kt) {
            const int kb = 4 * lg + 16 * kt;
            const int m  = lm + 16 * mt;
            w2f[mt][kt] = pack4(W2[(kb + 0) * CC + m], W2[(kb + 1) * CC + m],
                                W2[(kb + 2) * CC + m], W2[(kb + 3) * CC + m]);
        }

    f4 o[4];
#pragma unroll
    for (int mt = 0; mt < 4; ++mt) o[mt] = (f4){0.f, 0.f, 0.f, 0.f};
#pragma unroll
    for (int mt = 0; mt < 4; ++mt)
#pragma unroll
        for (int kt = 0; kt < 4; ++kt)
            o[mt] = mfma_bf16(w2f[mt][kt], gf[kt], o[mt]);

    float* sb = sbuf[wv];
    const int fbase = lm * 68;
    const int swz   = (l & 7) << 2;
#pragma unroll
    for (int mt = 0; mt < 4; ++mt)
#pragma unroll
        for (int r = 0; r < 4; ++r)
            sb[fbase + ((16 * mt + 4 * lg + r) ^ swz)] = o[mt][r];

    const f4 b2q = *(const f4*)(b2 + 4 * lm);
    const f4 lsq = *(const f4*)(ls + 4 * lm);

#pragma unroll
    for (int rr = 0; rr < 4; ++rr) {
        const int R   = rr * 4 + lg;
        const int col = 4 * lm;
        const f4 ov = *(const f4*)(&sb[R * 68 + (col ^ ((R & 7) << 2))]);
        const f4 xv = *(const f4*)(x + (size_t)(f0 + R) * CC + col);
        f4 res;
#pragma unroll
        for (int k = 0; k < 4; ++k)
            res[k] = fmaf(lsq[k], ov[k] + b2q[k], xv[k]);
        *(f4*)(out + (size_t)(f0 + R) * CC + col) = res;
    }
}

extern "C" void kernel_launch(void* const* d_in, const int* in_sizes, int n_in,
                              void* d_out, int out_size, void* d_ws, size_t ws_size,
                              hipStream_t stream) {
    const float* x    = (const float*)d_in[0];
    const float* attr = (const float*)d_in[1];
    const float* Wk   = (const float*)d_in[2];
    const float* cb   = (const float*)d_in[3];
    const float* lnw  = (const float*)d_in[4];
    const float* lnb  = (const float*)d_in[5];
    const float* W1   = (const float*)d_in[6];
    const float* b1   = (const float*)d_in[7];
    const float* W2   = (const float*)d_in[8];
    const float* b2   = (const float*)d_in[9];
    const float* ls   = (const float*)d_in[10];
    const int*   ei   = (const int*)d_in[11];
    float* out = (float*)d_out;

    int* cnt   = (int*)d_ws;                                // NN ints
    int* elist = cnt + NN;                                  // NN*MAXDEG ints
    unsigned int* xp = (unsigned int*)(elist + NN * MAXDEG); // NN*512 dwords (20.5 MB)

    xpack<<<NN / 4, 256, 0, stream>>>(x, xp, cnt);          // also zeroes cnt
    bucket_fill<<<(EE + 255) / 256, 256, 0, stream>>>(ei, cnt, elist);
    conv_mfma<<<NN / 4, 256, 0, stream>>>(xp, attr, Wk, cnt, elist, out);
    ln_mlp_mfma<<<938, 512, 0, stream>>>(x, cb, lnw, lnb, W1, b1, W2, b2, ls, out);
}

// Round 16
// 69.607 us; speedup vs baseline: 3.8518x; 3.8518x over previous
//
#include <hip/hip_runtime.h>
#include <math.h>

#define NN 10000
#define GG 12
#define CC 64
#define AA 3
#define EE 50000
#define LN_EPS 1e-5f
#define MAXDEG 64   // max in-degree cap; Poisson(E/N=5) max ~17, 64 is far beyond

typedef __attribute__((ext_vector_type(4))) float f4;
typedef __attribute__((ext_vector_type(4))) short s4;

union S4U { s4 s; unsigned int w[2]; };
union I2S { int i[2]; s4 s; };

// pack 4 f32 -> 4 bf16 (truncation) in frag element order k0..k3
__device__ __forceinline__ s4 pack4(float k0, float k1, float k2, float k3) {
    S4U t;
    t.w[0] = __builtin_amdgcn_perm(__float_as_uint(k1), __float_as_uint(k0), 0x07060302u);
    t.w[1] = __builtin_amdgcn_perm(__float_as_uint(k3), __float_as_uint(k2), 0x07060302u);
    return t.s;
}
// pack 2 f32 -> one dword [bf16(a) | bf16(b)<<16]
__device__ __forceinline__ unsigned int pack2(float a, float b) {
    return __builtin_amdgcn_perm(__float_as_uint(b), __float_as_uint(a), 0x07060302u);
}

__device__ __forceinline__ f4 mfma_bf16(s4 a, s4 b, f4 c) {
#if __has_builtin(__builtin_amdgcn_mfma_f32_16x16x16bf16_1k)
    return __builtin_amdgcn_mfma_f32_16x16x16bf16_1k(a, b, c, 0, 0, 0);
#else
    asm volatile("v_mfma_f32_16x16x16_bf16 %0, %1, %2, %0" : "+v"(c) : "v"(a), "v"(b));
    return c;
#endif
}

// ---------------- kernel 1: xpack (+ zero cnt, fused) ----------------
// wave = node. xp[n]: 2KB, lane l owns dwords n*512 + l*8..+7 in exact B-frag
// order; lg==3 (k pad) lanes are zero so conv needs no masking.
__global__ __launch_bounds__(256) void xpack(const float* __restrict__ x,
                                             unsigned int* __restrict__ xp,
                                             int* __restrict__ cnt) {
    const int gid = blockIdx.x * 256 + threadIdx.x;
    if (gid < NN) cnt[gid] = 0;

    const int l  = threadIdx.x & 63;
    const int n  = blockIdx.x * 4 + (threadIdx.x >> 6);
    const int lm = l & 15;
    const int lg = l >> 4;

    unsigned int d[8];
    if (lg < 3) {
        const char* xb = (const char*)(x + n * (GG * CC)) + lg * 1024 + lm * 4;
#pragma unroll
        for (int t = 0; t < 4; ++t) {
            const float v0 = *(const float*)(xb + t * 64 + 0 * 256);
            const float v1 = *(const float*)(xb + t * 64 + 1 * 256);
            const float v2 = *(const float*)(xb + t * 64 + 2 * 256);
            const float v3 = *(const float*)(xb + t * 64 + 3 * 256);
            d[2 * t]     = pack2(v0, v1);
            d[2 * t + 1] = pack2(v2, v3);
        }
    } else {
#pragma unroll
        for (int k = 0; k < 8; ++k) d[k] = 0u;
    }
    unsigned int* o = xp + (size_t)n * 512 + l * 8;
    *(uint4*)o       = make_uint4(d[0], d[1], d[2], d[3]);
    *(uint4*)(o + 4) = make_uint4(d[4], d[5], d[6], d[7]);
}

// ---------------- kernel 2: bucket edges by destination; pack e | src<<17 ----------------
__global__ __launch_bounds__(256) void bucket_fill(const int* __restrict__ ei,
                                                   int* __restrict__ cnt,
                                                   int* __restrict__ elist) {
    int e = blockIdx.x * 256 + threadIdx.x;
    if (e < EE) {
        int src = ei[e];
        int dst = ei[EE + e];
        int pos = atomicAdd(&cnt[dst], 1);
        if (pos < MAXDEG) elist[dst * MAXDEG + pos] = e | (src << 17);
    }
}

// ---------------- kernel 3: FUSED conv + LN + MLP + residual ----------------
// wave = node, 4 waves/block, no barriers (all LDS wave-private).
// Edge loop: verified r12 depth-2 pipeline (attr 2x dwordx4 -> LDS slot ->
// 3x ds_read_b128 -> 12 MFMA with packed-x B-frags). Epilogue: Wk combine +
// conv_bias -> LDS transpose (reusing the dead attr slots) -> verified ln_mlp
// body (LN 2-shfl, GEMM1, exact GELU, GEMM2, swizzled transpose, residual),
// with per-node L1-hot weight fragment loads and a 12-fiber store guard.
// agg never touches global memory.
__global__ __launch_bounds__(256) void conv_fused(
    const unsigned int* __restrict__ xp, const float* __restrict__ attr,
    const float* __restrict__ Wk,  const float* __restrict__ cb,
    const float* __restrict__ lnw, const float* __restrict__ lnb,
    const float* __restrict__ W1,  const float* __restrict__ b1,
    const float* __restrict__ W2,  const float* __restrict__ b2,
    const float* __restrict__ ls,  const float* __restrict__ x,
    const int* __restrict__ cnt,   const int* __restrict__ elist,
    float* __restrict__ out) {
    __shared__ float scratch[4][1088];   // 17.4 KB: per-wave; edge loop uses
                                         // [0..863] as 2 attr slots, epilogue
                                         // reuses [0..1087] as [16][68] tile

    const int l  = threadIdx.x & 63;
    const int w  = threadIdx.x >> 6;
    const int n  = blockIdx.x * 4 + w;
    const int lm = l & 15;
    const int lg = l >> 4;

    const int fbase = (lm < 12 && lg < 3) ? (lm * 36 + lg * 12) : 0;
    const int a1l   = (l < 44) ? l : 43;

    const int deg = min(cnt[n], MAXDEG);
    const int myE = elist[n * MAXDEG + l];

    // loop-invariant Wk fragments
    float wk[3][4];
#pragma unroll
    for (int a = 0; a < 3; ++a)
#pragma unroll
        for (int t = 0; t < 4; ++t)
            wk[a][t] = Wk[a * CC + lm + 16 * t];

    f4 acc[3][4];
#pragma unroll
    for (int a = 0; a < 3; ++a)
#pragma unroll
        for (int t = 0; t < 4; ++t) acc[a][t] = (f4){0.f, 0.f, 0.f, 0.f};

    f4 Aa0, Aa1, Ab0, Ab1;
    int4 Xa0, Xa1, Xb0, Xb1;

#define LOADE(idx, A0, A1, X0, X1)                                              \
    {                                                                           \
        const int p = __builtin_amdgcn_readlane(myE, (idx));                    \
        const char* ab = (const char*)(attr + (size_t)(p & 0x1FFFF) * 432);     \
        A0 = *(const f4*)(ab + 16 * l);                                         \
        A1 = *(const f4*)(ab + 1024 + 16 * a1l);                                \
        const int* xb = (const int*)(xp + (size_t)(p >> 17) * 512 + 8 * l);     \
        X0 = *(const int4*)xb;                                                  \
        X1 = *(const int4*)(xb + 4);                                            \
    }

#define STAGE(slot, A0, A1)                                                     \
    {                                                                           \
        float* sw = &scratch[w][(slot) * 432];                                  \
        *(f4*)(sw + 4 * l) = A0;                                                \
        if (l < 44) *(f4*)(sw + 256 + 4 * l) = A1;                              \
    }

#define COMPUTE(slot, X0, X1)                                                   \
    {                                                                           \
        I2S u0, u1, u2, u3;                                                     \
        u0.i[0] = X0.x; u0.i[1] = X0.y;                                         \
        u1.i[0] = X0.z; u1.i[1] = X0.w;                                         \
        u2.i[0] = X1.x; u2.i[1] = X1.y;                                         \
        u3.i[0] = X1.z; u3.i[1] = X1.w;                                         \
        const float* sr = &scratch[w][(slot) * 432] + fbase;                    \
        const f4 q0 = *(const f4*)(sr);                                         \
        const f4 q1 = *(const f4*)(sr + 4);                                     \
        const f4 q2 = *(const f4*)(sr + 8);                                     \
        const s4 af0 = pack4(q0[0], q0[3], q1[2], q2[1]);                       \
        const s4 af1 = pack4(q0[1], q1[0], q1[3], q2[2]);                       \
        const s4 af2 = pack4(q0[2], q1[1], q2[0], q2[3]);                       \
        acc[0][0] = mfma_bf16(af0, u0.s, acc[0][0]);                            \
        acc[1][0] = mfma_bf16(af1, u0.s, acc[1][0]);                            \
        acc[2][0] = mfma_bf16(af2, u0.s, acc[2][0]);                            \
        acc[0][1] = mfma_bf16(af0, u1.s, acc[0][1]);                            \
        acc[1][1] = mfma_bf16(af1, u1.s, acc[1][1]);                            \
        acc[2][1] = mfma_bf16(af2, u1.s, acc[2][1]);                            \
        acc[0][2] = mfma_bf16(af0, u2.s, acc[0][2]);                            \
        acc[1][2] = mfma_bf16(af1, u2.s, acc[1][2]);                            \
        acc[2][2] = mfma_bf16(af2, u2.s, acc[2][2]);                            \
        acc[0][3] = mfma_bf16(af0, u3.s, acc[0][3]);                            \
        acc[1][3] = mfma_bf16(af1, u3.s, acc[1][3]);                            \
        acc[2][3] = mfma_bf16(af2, u3.s, acc[2][3]);                            \
    }

    if (deg > 0) LOADE(0, Aa0, Aa1, Xa0, Xa1);
    if (deg > 1) LOADE(1, Ab0, Ab1, Xb0, Xb1);
    if (deg > 0) STAGE(0, Aa0, Aa1);

    for (int j = 0; j < deg; j += 2) {
        COMPUTE(0, Xa0, Xa1);
        if (j + 2 < deg) LOADE(j + 2, Aa0, Aa1, Xa0, Xa1);
        if (j + 1 < deg) {
            STAGE(1, Ab0, Ab1);
            COMPUTE(1, Xb0, Xb1);
            if (j + 3 < deg) LOADE(j + 3, Ab0, Ab1, Xb0, Xb1);
            if (j + 2 < deg) STAGE(0, Aa0, Aa1);
        }
    }

#undef LOADE
#undef STAGE
#undef COMPUTE

    // ================= fused epilogue (per-wave, no barriers) =================
    float* hb = &scratch[w][0];          // now viewed as [16][68] fiber tile

    // Wk combine + conv_bias, write T[g][c] rows 0..11 (lanes lg<3)
    if (lg < 3) {
#pragma unroll
        for (int t = 0; t < 4; ++t) {
            const float cbT = cb[lm + 16 * t];
#pragma unroll
            for (int r = 0; r < 4; ++r) {
                const float mv = fmaf(acc[0][t][r], wk[0][t],
                                 fmaf(acc[1][t][r], wk[1][t],
                                      acc[2][t][r] * wk[2][t])) + cbT;
                hb[(4 * lg + r) * 68 + lm + 16 * t] = mv;
            }
        }
    }
    // zero pad rows 12..15 (cols 0..63): 64 lanes x f4 covers 4x64
    *(f4*)(hb + (12 + lg) * 68 + 4 * lm) = (f4){0.f, 0.f, 0.f, 0.f};

    // fiber-major reload: lane (lm,lg) -> fiber lm, ch 4lg+16kt..+3
    f4 h4[4];
#pragma unroll
    for (int kt = 0; kt < 4; ++kt)
        h4[kt] = *(const f4*)(hb + lm * 68 + 4 * lg + 16 * kt);

    f4 lw4[4], lb4[4];
#pragma unroll
    for (int kt = 0; kt < 4; ++kt) {
        lw4[kt] = *(const f4*)(lnw + 4 * lg + 16 * kt);
        lb4[kt] = *(const f4*)(lnb + 4 * lg + 16 * kt);
    }

    // LayerNorm (verified 2-shfl pattern)
    float s = 0.f, s2 = 0.f;
#pragma unroll
    for (int kt = 0; kt < 4; ++kt)
#pragma unroll
        for (int j = 0; j < 4; ++j) {
            const float v = h4[kt][j];
            s += v; s2 += v * v;
        }
    s  += __shfl_xor(s, 16);  s  += __shfl_xor(s, 32);
    s2 += __shfl_xor(s2, 16); s2 += __shfl_xor(s2, 32);
    const float mu  = s * (1.f / 64.f);
    const float inv = rsqrtf(s2 * (1.f / 64.f) - mu * mu + LN_EPS);

    s4 hf[4];
#pragma unroll
    for (int kt = 0; kt < 4; ++kt) {
        const float n0 = (h4[kt][0] - mu) * inv * lw4[kt][0] + lb4[kt][0];
        const float n1 = (h4[kt][1] - mu) * inv * lw4[kt][1] + lb4[kt][1];
        const float n2 = (h4[kt][2] - mu) * inv * lw4[kt][2] + lb4[kt][2];
        const float n3 = (h4[kt][3] - mu) * inv * lw4[kt][3] + lb4[kt][3];
        hf[kt] = pack4(n0, n1, n2, n3);
    }

    // GEMM1 (W1^T frags loaded per node, L1-hot)
    f4 z[4];
#pragma unroll
    for (int mt = 0; mt < 4; ++mt) z[mt] = (f4){0.f, 0.f, 0.f, 0.f};
#pragma unroll
    for (int mt = 0; mt < 4; ++mt)
#pragma unroll
        for (int kt = 0; kt < 4; ++kt) {
            const int kb = 4 * lg + 16 * kt;
            const int m  = lm + 16 * mt;
            const s4 wf = pack4(W1[(kb + 0) * CC + m], W1[(kb + 1) * CC + m],
                                W1[(kb + 2) * CC + m], W1[(kb + 3) * CC + m]);
            z[mt] = mfma_bf16(wf, hf[kt], z[mt]);
        }

    // + b1, exact GELU
    s4 gf[4];
#pragma unroll
    for (int mt = 0; mt < 4; ++mt) {
        const f4 b14 = *(const f4*)(b1 + 16 * mt + 4 * lg);
        float g[4];
#pragma unroll
        for (int r = 0; r < 4; ++r) {
            const float zz = z[mt][r] + b14[r];
            g[r] = 0.5f * zz * (1.f + erff(zz * 0.70710678118654752f));
        }
        gf[mt] = pack4(g[0], g[1], g[2], g[3]);
    }

    // GEMM2
    f4 o[4];
#pragma unroll
    for (int mt = 0; mt < 4; ++mt) o[mt] = (f4){0.f, 0.f, 0.f, 0.f};
#pragma unroll
    for (int mt = 0; mt < 4; ++mt)
#pragma unroll
        for (int kt = 0; kt < 4; ++kt) {
            const int kb = 4 * lg + 16 * kt;
            const int m  = lm + 16 * mt;
            const s4 wf = pack4(W2[(kb + 0) * CC + m], W2[(kb + 1) * CC + m],
                                W2[(kb + 2) * CC + m], W2[(kb + 3) * CC + m]);
            o[mt] = mfma_bf16(wf, gf[kt], o[mt]);
        }

    // transpose through XOR-swizzled LDS (reuse hb), then residual + store.
    // Only 12 fibers per node are real: R = rr*4+lg with rr<3 covers 0..11.
    const int fb2 = lm * 68;
    const int swz = (l & 7) << 2;
#pragma unroll
    for (int mt = 0; mt < 4; ++mt)
#pragma unroll
        for (int r = 0; r < 4; ++r)
            hb[fb2 + ((16 * mt + 4 * lg + r) ^ swz)] = o[mt][r];

    const f4 b2q = *(const f4*)(b2 + 4 * lm);
    const f4 lsq = *(const f4*)(ls + 4 * lm);
    const int f0 = n * GG;

#pragma unroll
    for (int rr = 0; rr < 3; ++rr) {
        const int R   = rr * 4 + lg;         // 0..11
        const int col = 4 * lm;
        const f4 ov = *(const f4*)(&hb[R * 68 + (col ^ ((R & 7) << 2))]);
        const f4 xv = *(const f4*)(x + (size_t)(f0 + R) * CC + col);
        f4 res;
#pragma unroll
        for (int k = 0; k < 4; ++k)
            res[k] = fmaf(lsq[k], ov[k] + b2q[k], xv[k]);
        *(f4*)(out + (size_t)(f0 + R) * CC + col) = res;
    }
}

extern "C" void kernel_launch(void* const* d_in, const int* in_sizes, int n_in,
                              void* d_out, int out_size, void* d_ws, size_t ws_size,
                              hipStream_t stream) {
    const float* x    = (const float*)d_in[0];
    const float* attr = (const float*)d_in[1];
    const float* Wk   = (const float*)d_in[2];
    const float* cb   = (const float*)d_in[3];
    const float* lnw  = (const float*)d_in[4];
    const float* lnb  = (const float*)d_in[5];
    const float* W1   = (const float*)d_in[6];
    const float* b1   = (const float*)d_in[7];
    const float* W2   = (const float*)d_in[8];
    const float* b2   = (const float*)d_in[9];
    const float* ls   = (const float*)d_in[10];
    const int*   ei   = (const int*)d_in[11];
    float* out = (float*)d_out;

    int* cnt   = (int*)d_ws;                                // NN ints
    int* elist = cnt + NN;                                  // NN*MAXDEG ints
    unsigned int* xp = (unsigned int*)(elist + NN * MAXDEG); // NN*512 dwords (20.5 MB)

    xpack<<<NN / 4, 256, 0, stream>>>(x, xp, cnt);          // also zeroes cnt
    bucket_fill<<<(EE + 255) / 256, 256, 0, stream>>>(ei, cnt, elist);
    conv_fused<<<NN / 4, 256, 0, stream>>>(xp, attr, Wk, cb, lnw, lnb, W1, b1,
                                           W2, b2, ls, x, cnt, elist, out);
}